// Round 5
// baseline (149.873 us; speedup 1.0000x reference)
//
#include <hip/hip_runtime.h>
#include <cstdint>
#include <cstddef>

// Problem: B=8,S=2048,E=512,FFN=2048,Q=8 -> M=16384, K=2048, N=512.
// Round-5: BM=64, BN=256, 256 thr (4 waves, 64x64 wave tiles), grid=512
// -> 2 blocks/CU (the round-3/4 structure had grid=256 = 1 block/CU, so
// every barrier stalled the whole CU). w1/b1 no longer LDS-resident:
// w1 slice regs are prefetched from L2 one iteration ahead inside the
// counted-vmcnt queue. LDS = As 8K + Bs 32K + b1s 8K = 48 KB.

typedef __attribute__((ext_vector_type(8))) short s16x8;
typedef __attribute__((ext_vector_type(4))) float f32x4;

__device__ __forceinline__ unsigned short f2bf(float f) {
  unsigned int u = __float_as_uint(f);
  unsigned int r = u + 0x7fffu + ((u >> 16) & 1u);
  return (unsigned short)(r >> 16);
}

__device__ __forceinline__ void async_copy16(const void* g, void* l) {
  __builtin_amdgcn_global_load_lds(
      (const __attribute__((address_space(1))) void*)(uintptr_t)g,
      (__attribute__((address_space(3))) void*)(unsigned int)(uintptr_t)l,
      16, 0, 0);
}

// ---------------------------------------------------------------------------
// Kernel 1: build w2b image (identical to round 4; BN=256 halves, nt=n>>8).
// Layout: [nt(2)][slice s(64)][chunk ci(1024)]x16B,
// ci = nhi*64 + quad*16 + nlo; data = bf16(w2[n][s*32+quad*8 .. +7]).
// ---------------------------------------------------------------------------
__global__ __launch_bounds__(256) void k_w2(const float* __restrict__ w2,
                                            unsigned short* __restrict__ img) {
  const int n = blockIdx.x;   // 0..511
  const int t = threadIdx.x;
  const int s = t >> 2, quad = t & 3;
  const float* src = w2 + (size_t)n * 2048 + t * 8;  // coalesced read
  float4 a = *(const float4*)src;
  float4 b = *(const float4*)(src + 4);
  uint4 pk;
  pk.x = f2bf(a.x) | ((unsigned)f2bf(a.y) << 16);
  pk.y = f2bf(a.z) | ((unsigned)f2bf(a.w) << 16);
  pk.z = f2bf(b.x) | ((unsigned)f2bf(b.y) << 16);
  pk.w = f2bf(b.z) | ((unsigned)f2bf(b.w) << 16);
  const int nt = n >> 8, nl = n & 255, nhi = nl >> 4, nlo = nl & 15;
  const size_t ci = (size_t)(nt * 64 + s) * 1024 + nhi * 64 + quad * 16 + nlo;
  *(uint4*)(img + ci * 8) = pk;
}

// ---------------------------------------------------------------------------
// Kernel 2 (fused): C[m][n] = sum_k relu(z[m]·w1[k]+b1[k]) * w2[n][k] + b2[n]
// ---------------------------------------------------------------------------
__global__ __launch_bounds__(256, 2) void k_fused(
    const float* __restrict__ x, const float* __restrict__ ry,
    const float* __restrict__ w1, const float* __restrict__ b1,
    const unsigned short* __restrict__ w2b, const float* __restrict__ b2,
    float* __restrict__ C) {
  __shared__ unsigned short As[2][64 * 32];   // 2 x 4 KB slot-permuted image
  __shared__ unsigned short Bs[2][256 * 32];  // 2 x 16 KB linear-frag image
  __shared__ float b1s[2048];                 // 8 KB -> 48 KB total

  const int t = threadIdx.x;       // 0..255
  const int lane = t & 63;
  const int w = t >> 6;            // wave 0..3 -> wn = w*64
  const int mt = (int)(blockIdx.x >> 1);
  const int nt = (int)(blockIdx.x & 1);
  const int r0 = mt * 64;
  const int c0 = nt * 256;
  const int fp = t & 15;  // f-pair index within the 32-wide K-step
  const int rq = t >> 4;  // row-quad 0..15: rows rq*4 .. rq*4+3

  // ---- prologue group 1: x/ry loads + z (retired before group 2) ----
  float zr[4][8];
  {
    float4 ra = *(const float4*)ry;
    float4 rb = *(const float4*)(ry + 4);
    float cy[8] = {__cosf(ra.x), __cosf(ra.y), __cosf(ra.z), __cosf(ra.w),
                   __cosf(rb.x), __cosf(rb.y), __cosf(rb.z), __cosf(rb.w)};
#pragma unroll
    for (int r = 0; r < 4; ++r) {
      const float* xr = x + (size_t)(r0 + rq * 4 + r) * 512;
      float4 x0 = *(const float4*)xr;
      float4 x1 = *(const float4*)(xr + 4);
      zr[r][0] = __cosf(x0.x) * cy[0];
      zr[r][1] = __cosf(x0.y) * cy[1];
      zr[r][2] = __cosf(x0.z) * cy[2];
      zr[r][3] = __cosf(x0.w) * cy[3];
      zr[r][4] = __cosf(x1.x) * cy[4];
      zr[r][5] = __cosf(x1.y) * cy[5];
      zr[r][6] = __cosf(x1.z) * cy[6];
      zr[r][7] = __cosf(x1.w) * cy[7];
    }
  }
  __builtin_amdgcn_sched_barrier(0);

  // ---- group 2: w1 slice-0/1 register sets (2 rows = 16 floats each) ----
  f32x4 wA0, wA1, wA2, wA3, wB0, wB1, wB2, wB3;
  {
    const f32x4* p0 = (const f32x4*)(w1 + fp * 16);        // slice 0
    wA0 = p0[0]; wA1 = p0[1]; wA2 = p0[2]; wA3 = p0[3];
    const f32x4* p1 = (const f32x4*)(w1 + 256 + fp * 16);  // slice 1
    wB0 = p1[0]; wB1 = p1[1]; wB2 = p1[2]; wB3 = p1[3];
  }
  __builtin_amdgcn_sched_barrier(0);

  // ---- group 3: async staging (order pinned after w1 loads) ----
  const unsigned short* gB = w2b + (size_t)nt * 524288 + t * 8;
  char* lB = (char*)Bs + t * 16;
  auto stage = [&](int s, int buf) {
#pragma unroll
    for (int p = 0; p < 4; ++p)
      async_copy16(gB + (size_t)s * 8192 + p * 2048,
                   lB + buf * 16384 + p * 4096);
  };
  stage(0, 0);
  async_copy16(b1 + (size_t)t * 4, (char*)b1s + (size_t)t * 16);
  async_copy16(b1 + (size_t)(t + 256) * 4, (char*)b1s + (size_t)(t + 256) * 16);
  stage(1, 1);

  // drain w1A/w1B + stage0 + b1; keep stage1's 4 loads in flight
  asm volatile("s_waitcnt vmcnt(4) lgkmcnt(0)" ::: "memory");
  __builtin_amdgcn_sched_barrier(0);
  __builtin_amdgcn_s_barrier();

  // As image write slot (identical formulas to round 4, 64-row scale):
  char* aswr = (char*)As + (rq >> 2) * 1024 +
               (((((fp >> 3) & 1) << 3) | ((rq & 3) << 1) | ((fp >> 2) & 1)) << 4) +
               (fp & 3) * 4;
  auto act = [&](int s, int buf, const f32x4& v0, const f32x4& v1,
                 const f32x4& v2, const f32x4& v3) {
    float b0 = b1s[s * 32 + fp * 2];
    float b1v = b1s[s * 32 + fp * 2 + 1];
    char* dst = aswr + buf * 4096;
#pragma unroll
    for (int r = 0; r < 4; ++r) {
      float h0 = b0, h1 = b1v;
      h0 += zr[r][0] * v0[0]; h1 += zr[r][0] * v2[0];
      h0 += zr[r][1] * v0[1]; h1 += zr[r][1] * v2[1];
      h0 += zr[r][2] * v0[2]; h1 += zr[r][2] * v2[2];
      h0 += zr[r][3] * v0[3]; h1 += zr[r][3] * v2[3];
      h0 += zr[r][4] * v1[0]; h1 += zr[r][4] * v3[0];
      h0 += zr[r][5] * v1[1]; h1 += zr[r][5] * v3[1];
      h0 += zr[r][6] * v1[2]; h1 += zr[r][6] * v3[2];
      h0 += zr[r][7] * v1[3]; h1 += zr[r][7] * v3[3];
      h0 = fmaxf(h0, 0.0f);
      h1 = fmaxf(h1, 0.0f);
      unsigned int u;
      asm("v_cvt_pk_bf16_f32 %0, %1, %2" : "=v"(u) : "v"(h0), "v"(h1));
      *(unsigned int*)(dst + r * 256) = u;
    }
  };

  act(0, 0, wA0, wA1, wA2, wA3);  // As[0]; visible after C(0)'s lgkm+barrier

  // frag pointers (wave tile: all 64 rows x 64 cols at wn = w*64)
  const int wn = w * 64;
  const int fr = lane & 15;
  const int quad = lane >> 4;
  const int slotA = ((fr & 3) << 4) | (((quad >> 1) & 1) << 3) |
                    ((fr >> 2) << 1) | (quad & 1);
  const char* pAb = (const char*)As + slotA * 16;
  const char* pBb = (const char*)Bs + w * 4096 + quad * 256 + fr * 16;

  f32x4 acc[4][4];
#pragma unroll
  for (int i = 0; i < 4; ++i)
#pragma unroll
    for (int j = 0; j < 4; ++j) acc[i][j] = (f32x4){0.f, 0.f, 0.f, 0.f};

  // body(kt): C-wait; prefetch w1(kt+2)->load set; frags(kt); act(kt+1) with
  // use set; MFMA; E-wait; stage Bs(kt+2). vmcnt(4) at C drains exactly
  // {w1(kt+1)} (steady state), leaving stage(kt+1)'s 4 loads in flight.
  auto body = [&](int kt, const f32x4& u0, const f32x4& u1, const f32x4& u2,
                  const f32x4& u3, f32x4& l0, f32x4& l1, f32x4& l2,
                  f32x4& l3) {
    asm volatile("s_waitcnt vmcnt(4) lgkmcnt(0)" ::: "memory");
    __builtin_amdgcn_sched_barrier(0);
    __builtin_amdgcn_s_barrier();

    {
      const f32x4* p = (const f32x4*)(w1 + (size_t)(kt + 2) * 256 + fp * 16);
      l0 = p[0]; l1 = p[1]; l2 = p[2]; l3 = p[3];
    }
    const int cur = kt & 1;
    s16x8 af[4], bfv[4];
    const char* pA = pAb + cur * 4096;
    const char* pB = pBb + cur * 16384;
#pragma unroll
    for (int i = 0; i < 4; ++i) af[i] = *(const s16x8*)(pA + i * 1024);
#pragma unroll
    for (int j = 0; j < 4; ++j) bfv[j] = *(const s16x8*)(pB + j * 1024);

    act(kt + 1, cur ^ 1, u0, u1, u2, u3);

    __builtin_amdgcn_s_setprio(1);
#pragma unroll
    for (int i = 0; i < 4; ++i)
#pragma unroll
      for (int j = 0; j < 4; ++j)
        acc[i][j] = __builtin_amdgcn_mfma_f32_16x16x32_bf16(af[i], bfv[j],
                                                            acc[i][j], 0, 0, 0);
    __builtin_amdgcn_s_setprio(0);

    asm volatile("s_waitcnt lgkmcnt(0)" ::: "memory");
    __builtin_amdgcn_sched_barrier(0);
    __builtin_amdgcn_s_barrier();

    stage(kt + 2, cur);
  };

  for (int kt = 0; kt < 62; kt += 2) {
    body(kt, wB0, wB1, wB2, wB3, wA0, wA1, wA2, wA3);      // act(odd) uses B
    body(kt + 1, wA0, wA1, wA2, wA3, wB0, wB1, wB2, wB3);  // act(even) uses A
  }

  // ---- tail: kt = 62 (act 63, no more prefetch/stage), kt = 63 ----
  {
    asm volatile("s_waitcnt vmcnt(4) lgkmcnt(0)" ::: "memory");
    __builtin_amdgcn_sched_barrier(0);
    __builtin_amdgcn_s_barrier();
    s16x8 af[4], bfv[4];
#pragma unroll
    for (int i = 0; i < 4; ++i) af[i] = *(const s16x8*)(pAb + i * 1024);
#pragma unroll
    for (int j = 0; j < 4; ++j) bfv[j] = *(const s16x8*)(pBb + j * 1024);
    act(63, 1, wB0, wB1, wB2, wB3);
    __builtin_amdgcn_s_setprio(1);
#pragma unroll
    for (int i = 0; i < 4; ++i)
#pragma unroll
      for (int j = 0; j < 4; ++j)
        acc[i][j] = __builtin_amdgcn_mfma_f32_16x16x32_bf16(af[i], bfv[j],
                                                            acc[i][j], 0, 0, 0);
    __builtin_amdgcn_s_setprio(0);
    asm volatile("s_waitcnt lgkmcnt(0)" ::: "memory");
    __builtin_amdgcn_sched_barrier(0);
    __builtin_amdgcn_s_barrier();
  }
  {
    asm volatile("s_waitcnt vmcnt(0) lgkmcnt(0)" ::: "memory");
    __builtin_amdgcn_sched_barrier(0);
    __builtin_amdgcn_s_barrier();
    s16x8 af[4], bfv[4];
#pragma unroll
    for (int i = 0; i < 4; ++i)
      af[i] = *(const s16x8*)(pAb + 4096 + i * 1024);
#pragma unroll
    for (int j = 0; j < 4; ++j)
      bfv[j] = *(const s16x8*)(pBb + 16384 + j * 1024);
#pragma unroll
    for (int i = 0; i < 4; ++i)
#pragma unroll
      for (int j = 0; j < 4; ++j)
        acc[i][j] = __builtin_amdgcn_mfma_f32_16x16x32_bf16(af[i], bfv[j],
                                                            acc[i][j], 0, 0, 0);
  }

  // epilogue: C/D layout col = lane&15, row = quad*4 + reg (m89/m91 verified)
  float bias[4];
#pragma unroll
  for (int j = 0; j < 4; ++j) bias[j] = b2[c0 + wn + j * 16 + fr];
#pragma unroll
  for (int i = 0; i < 4; ++i) {
    const int rbase = r0 + i * 16 + quad * 4;
#pragma unroll
    for (int rr = 0; rr < 4; ++rr) {
      float* crow = C + (size_t)(rbase + rr) * 512;
#pragma unroll
      for (int j = 0; j < 4; ++j)
        crow[c0 + wn + j * 16 + fr] = acc[i][j][rr] + bias[j];
    }
  }
}

// ---------------------------------------------------------------------------
// Emergency fallback (only if ws_size is tiny): fully fused fp32, 1 row/block.
// ---------------------------------------------------------------------------
__global__ __launch_bounds__(256) void k_naive(
    const float* __restrict__ x, const float* __restrict__ ry,
    const float* __restrict__ w1, const float* __restrict__ b1,
    const float* __restrict__ w2, const float* __restrict__ b2,
    float* __restrict__ out) {
  __shared__ float zsh[8];
  __shared__ float acts[2048];
  const int r = blockIdx.x;
  const int t = threadIdx.x;
  if (t < 8) zsh[t] = __cosf(x[(size_t)r * 512 + t]) * __cosf(ry[t]);
  __syncthreads();
  float z[8];
#pragma unroll
  for (int q = 0; q < 8; ++q) z[q] = zsh[q];
#pragma unroll
  for (int i = 0; i < 8; ++i) {
    const int f = t * 8 + i;
    const float* wr = w1 + (size_t)f * 8;
    float4 a = *(const float4*)wr;
    float4 b = *(const float4*)(wr + 4);
    float h = b1[f] + z[0] * a.x + z[1] * a.y + z[2] * a.z + z[3] * a.w +
              z[4] * b.x + z[5] * b.y + z[6] * b.z + z[7] * b.w;
    acts[f] = fmaxf(h, 0.0f);
  }
  __syncthreads();
  for (int ee = 0; ee < 2; ++ee) {
    const int e = t + ee * 256;
    const float* wr = w2 + (size_t)e * 2048;
    float acc = b2[e];
    for (int f = 0; f < 2048; f += 4) {
      float4 wv = *(const float4*)(wr + f);
      float4 av = *(const float4*)(acts + f);
      acc += av.x * wv.x + av.y * wv.y + av.z * wv.z + av.w * wv.w;
    }
    out[(size_t)r * 512 + e] = acc;
  }
}

extern "C" void kernel_launch(void* const* d_in, const int* in_sizes, int n_in,
                              void* d_out, int out_size, void* d_ws,
                              size_t ws_size, hipStream_t stream) {
  const float* x  = (const float*)d_in[0];
  const float* ry = (const float*)d_in[1];
  const float* w1 = (const float*)d_in[2];
  const float* b1 = (const float*)d_in[3];
  const float* w2 = (const float*)d_in[4];
  const float* b2 = (const float*)d_in[5];
  float* out = (float*)d_out;

  const size_t w2b_bytes = (size_t)512 * 2048 * 2;  // 2 MB bf16 w2 image
  if (ws_size < w2b_bytes) {
    k_naive<<<dim3(16384), dim3(256), 0, stream>>>(x, ry, w1, b1, w2, b2, out);
    return;
  }
  unsigned short* w2b = (unsigned short*)d_ws;
  k_w2<<<dim3(512), dim3(256), 0, stream>>>(w2, w2b);
  k_fused<<<dim3(512), dim3(256), 0, stream>>>(x, ry, w1, b1, w2b, b2, out);
}